// Round 2
// baseline (503.058 us; speedup 1.0000x reference)
//
#include <hip/hip_runtime.h>
#include <cstddef>

#define NN 256          // nodes
#define VD 64           // V
#define ED 64           // E
#define SD 16           // S
#define HD 16           // H
#define EPS 65280       // edges per s = N*(N-1)

__device__ __forceinline__ float fast_tanh(float x) {
    float e = __expf(2.0f * x);
    float r = __builtin_amdgcn_rcpf(e + 1.0f);
    return 1.0f - 2.0f * r;
}

// ---------------- Kernel P: per-node first-layer tables ----------------
// a[s,n,i] = sum_k v0[s,n,k] * we1[k,i]        (recv half)
// b[s,n,i] = sum_k v0[s,n,k] * we1[64+k,i]     (send half)
__global__ __launch_bounds__(256) void precompute_ab(
    const float* __restrict__ v0, const float* __restrict__ we1,
    float* __restrict__ a_tab, float* __restrict__ b_tab) {
    int t = threadIdx.x;
    int i = t & 15;
    int nl = t >> 4;
    int node = blockIdx.x * 16 + nl;          // s*256+n, 0..4095
    const float* vrow = v0 + (size_t)node * VD;
    float a = 0.f, b = 0.f;
    #pragma unroll
    for (int k = 0; k < VD; ++k) {
        float x = vrow[k];
        a += x * we1[k * HD + i];
        b += x * we1[(VD + k) * HD + i];
    }
    a_tab[node * HD + i] = a;
    b_tab[node * HD + i] = b;
}

// ---------------- Kernel A: ev = sum_j e0[s,n,j,:]; dv = MLP(ev) ----------------
// 4-wide unrolled row reduction: 4 independent accumulators => 4 outstanding
// 1KB wave-loads per iteration.
__global__ __launch_bounds__(256) void dv_kernel(
    const float* __restrict__ e0,
    const float* __restrict__ wv1, const float* __restrict__ bv1,
    const float* __restrict__ wv2, const float* __restrict__ bv2,
    float* __restrict__ dv_out) {
    __shared__ float red[1024];   // 16 groups x 64 e
    __shared__ float ev_s[64];
    __shared__ float h_s[16];
    int t = threadIdx.x;
    int node = blockIdx.x;                    // s*256+n
    const float* base = e0 + (size_t)node * 255 * ED;
    int c = t & 15;                           // float4 column (e/4)
    int g = t >> 4;                           // row group (0..15)
    const float* p0 = base + (size_t)g * ED + c * 4;
    float4 a0 = make_float4(0, 0, 0, 0), a1 = a0, a2 = a0, a3 = a0;
    #pragma unroll
    for (int jj = 0; jj < 3; ++jj) {
        const float* p = p0 + (size_t)jj * 64 * ED;
        float4 v0q = *(const float4*)(p);
        float4 v1q = *(const float4*)(p + 16 * ED);
        float4 v2q = *(const float4*)(p + 32 * ED);
        float4 v3q = *(const float4*)(p + 48 * ED);
        a0.x += v0q.x; a0.y += v0q.y; a0.z += v0q.z; a0.w += v0q.w;
        a1.x += v1q.x; a1.y += v1q.y; a1.z += v1q.z; a1.w += v1q.w;
        a2.x += v2q.x; a2.y += v2q.y; a2.z += v2q.z; a2.w += v2q.w;
        a3.x += v3q.x; a3.y += v3q.y; a3.z += v3q.z; a3.w += v3q.w;
    }
    {   // tail: rows g+192, g+208, g+224 always; g+240 only if g<15
        const float* p = p0 + (size_t)192 * ED;
        float4 v0q = *(const float4*)(p);
        float4 v1q = *(const float4*)(p + 16 * ED);
        float4 v2q = *(const float4*)(p + 32 * ED);
        a0.x += v0q.x; a0.y += v0q.y; a0.z += v0q.z; a0.w += v0q.w;
        a1.x += v1q.x; a1.y += v1q.y; a1.z += v1q.z; a1.w += v1q.w;
        a2.x += v2q.x; a2.y += v2q.y; a2.z += v2q.z; a2.w += v2q.w;
        if (g < 15) {
            float4 v3q = *(const float4*)(p + 48 * ED);
            a3.x += v3q.x; a3.y += v3q.y; a3.z += v3q.z; a3.w += v3q.w;
        }
    }
    float4 acc;
    acc.x = (a0.x + a1.x) + (a2.x + a3.x);
    acc.y = (a0.y + a1.y) + (a2.y + a3.y);
    acc.z = (a0.z + a1.z) + (a2.z + a3.z);
    acc.w = (a0.w + a1.w) + (a2.w + a3.w);
    *(float4*)(red + g * 64 + c * 4) = acc;
    __syncthreads();
    if (t < 64) {
        float s = 0.f;
        #pragma unroll
        for (int gg = 0; gg < 16; ++gg) s += red[gg * 64 + t];
        ev_s[t] = s;
    }
    __syncthreads();
    if (t < 16) {
        float ah = bv1[t];
        #pragma unroll
        for (int e = 0; e < 64; ++e) ah += ev_s[e] * wv1[e * HD + t];
        h_s[t] = fast_tanh(ah);
    }
    __syncthreads();
    if (t < 64) {
        float o = bv2[t];
        #pragma unroll
        for (int i = 0; i < HD; ++i) o += h_s[i] * wv2[i * VD + t];
        dv_out[(size_t)node * VD + t] = o;
    }
}

// ---------------- Kernel B: de = tanh(a[recv]+b[send]+be1) @ we2 + be2 ----------------
// 64 edges per block. Phase 1: 256 threads compute h (4 i's each) into LDS
// (stride 20 floats, conflict-free b128 writes). Phase 2: wave w handles edges
// [w*16, w*16+16) in 4 groups of 4; lane = (edge-in-group q, col-quad c).
// we2 held per-lane as 16 float4s; 16 LDS b128 reads/wave (bank-disjoint),
// 4x global_store_dwordx4/wave (1KB contiguous each).
__global__ __launch_bounds__(256) void de_kernel(
    const float* __restrict__ a_tab, const float* __restrict__ b_tab,
    const float* __restrict__ we2, const float* __restrict__ be1,
    const float* __restrict__ be2,
    const int* __restrict__ recv_idx, const int* __restrict__ send_idx,
    float* __restrict__ de_out) {
    __shared__ float h_s[64 * 20];            // 5120 B
    int t = threadIdx.x;
    int s = blockIdx.y;
    int tile = blockIdx.x;                    // 0..1019
    int p = t & 63;
    int iq = t >> 6;                          // 0..3
    int eg = tile * 64 + p;                   // edge index within s

    // ---- phase 1: activations into LDS ----
    int r  = recv_idx[eg];
    int sd = send_idx[eg];
    const float4 av = *(const float4*)(a_tab + ((s << 8) + r)  * HD + iq * 4);
    const float4 bv = *(const float4*)(b_tab + ((s << 8) + sd) * HD + iq * 4);
    const float4 b1 = *(const float4*)(be1 + iq * 4);
    float4 hv;
    hv.x = fast_tanh(av.x + bv.x + b1.x);
    hv.y = fast_tanh(av.y + bv.y + b1.y);
    hv.z = fast_tanh(av.z + bv.z + b1.z);
    hv.w = fast_tanh(av.w + bv.w + b1.w);
    *(float4*)(h_s + p * 20 + iq * 4) = hv;

    // per-lane we2 quad: lane (q = L>>4, c = L&15) holds we2[i][4c..4c+3]
    int L = t & 63;
    int w = t >> 6;                           // wave id
    int q = L >> 4;                           // edge-in-group 0..3
    int c = L & 15;                           // col-quad 0..15
    float4 w2q[16];
    #pragma unroll
    for (int i = 0; i < HD; ++i) w2q[i] = *(const float4*)(we2 + i * ED + c * 4);
    const float4 bias = *(const float4*)(be2 + c * 4);
    __syncthreads();

    // ---- phase 2 ----
    size_t outbase = ((size_t)s * EPS + (size_t)tile * 64) * ED;
    #pragma unroll
    for (int g2 = 0; g2 < 4; ++g2) {
        int pp = w * 16 + g2 * 4 + q;         // this lane's edge
        const float* hp = h_s + pp * 20;
        float4 h0 = *(const float4*)(hp);
        float4 h1 = *(const float4*)(hp + 4);
        float4 h2 = *(const float4*)(hp + 8);
        float4 h3 = *(const float4*)(hp + 12);
        float4 o = bias;
        #pragma unroll
        for (int j = 0; j < 4; ++j) {
            float hj0 = (&h0.x)[j], hj1 = (&h1.x)[j], hj2 = (&h2.x)[j], hj3 = (&h3.x)[j];
            o.x += hj0 * w2q[j].x      + hj1 * w2q[4 + j].x  + hj2 * w2q[8 + j].x  + hj3 * w2q[12 + j].x;
            o.y += hj0 * w2q[j].y      + hj1 * w2q[4 + j].y  + hj2 * w2q[8 + j].y  + hj3 * w2q[12 + j].y;
            o.z += hj0 * w2q[j].z      + hj1 * w2q[4 + j].z  + hj2 * w2q[8 + j].z  + hj3 * w2q[12 + j].z;
            o.w += hj0 * w2q[j].w      + hj1 * w2q[4 + j].w  + hj2 * w2q[8 + j].w  + hj3 * w2q[12 + j].w;
        }
        *(float4*)(de_out + outbase + (size_t)pp * ED + c * 4) = o;
    }
}

extern "C" void kernel_launch(void* const* d_in, const int* in_sizes, int n_in,
                              void* d_out, int out_size, void* d_ws, size_t ws_size,
                              hipStream_t stream) {
    // inputs: t, v0, e0, wv1, bv1, wv2, bv2, we1, be1, we2, be2, recv_idx, send_idx
    const float* v0   = (const float*)d_in[1];
    const float* e0   = (const float*)d_in[2];
    const float* wv1  = (const float*)d_in[3];
    const float* bv1  = (const float*)d_in[4];
    const float* wv2  = (const float*)d_in[5];
    const float* bv2  = (const float*)d_in[6];
    const float* we1  = (const float*)d_in[7];
    const float* be1  = (const float*)d_in[8];
    const float* we2  = (const float*)d_in[9];
    const float* be2  = (const float*)d_in[10];
    const int* recv_idx = (const int*)d_in[11];
    const int* send_idx = (const int*)d_in[12];

    float* dv_out = (float*)d_out;                       // S*N*V = 262144
    float* de_out = dv_out + (size_t)SD * NN * VD;       // S*N*(N-1)*E
    float* a_tab  = (float*)d_ws;                        // 4096*16 floats
    float* b_tab  = a_tab + 4096 * HD;                   // 4096*16 floats

    precompute_ab<<<256, 256, 0, stream>>>(v0, we1, a_tab, b_tab);
    dv_kernel<<<SD * NN, 256, 0, stream>>>(e0, wv1, bv1, wv2, bv2, dv_out);
    de_kernel<<<dim3(EPS / 64, SD), 256, 0, stream>>>(a_tab, b_tab, we2, be1, be2,
                                                      recv_idx, send_idx, de_out);
}